// Round 10
// baseline (72.979 us; speedup 1.0000x reference)
//
#include <hip/hip_runtime.h>
#include <math.h>

// Banded unbalanced Sinkhorn OT -> disparity. ONE WAVE per (b,h) problem:
// no inter-wave barriers at all. Lane L owns 6 consecutive cols (L<60) and
// 6 consecutive rows (L<52); band sums are lane-local v_dot2_f32_f16 chains
// over register-resident fp16 weights. E=2^f, G=2^g live in LDS fp16 with
// even/odd shifted replicas so each lane's window is parity-uniform and read
// as aligned half2 (b32). Uniform shifts deferred to a final scalar
// recurrence over 21 reduction values (per-lane partials -> LDS -> DPP).

typedef _Float16 half1;
typedef _Float16 half2v __attribute__((ext_vector_type(2)));

#define MAXD   48
#define WROWS  312
#define CCOLS  360
#define NITER  10
#define NACC   21

__device__ __forceinline__ half2v h2(unsigned v) { return __builtin_bit_cast(half2v, v); }
__device__ __forceinline__ half2v pack2(unsigned short a, unsigned short b) {
    unsigned u = (unsigned)a | ((unsigned)b << 16);
    return __builtin_bit_cast(half2v, u);
}
__device__ __forceinline__ unsigned packf(float x, float y) {
    half2v v; v[0] = (half1)x; v[1] = (half1)y;
    return __builtin_bit_cast(unsigned, v);
}
__device__ __forceinline__ unsigned short f16b(float x) {
    half1 v = (half1)x; return __builtin_bit_cast(unsigned short, v);
}

template <int CTRL>
__device__ __forceinline__ float dpp_add(float x, float acc) {
    int y = __builtin_amdgcn_update_dpp(0, __float_as_int(x), CTRL, 0xf, 0xf, true);
    return acc + __int_as_float(y);
}
// 64-lane sum; valid in lane 63.
__device__ __forceinline__ float dpp_sum64(float x) {
    x = dpp_add<0x111>(x, x);
    x = dpp_add<0x112>(x, x);
    x = dpp_add<0x114>(x, x);
    x = dpp_add<0x118>(x, x);
    x = dpp_add<0x142>(x, x);
    x = dpp_add<0x143>(x, x);
    return x;
}

__global__ __launch_bounds__(64, 1)
void ot_disp_kernel(const float* __restrict__ scores, float* __restrict__ out) {
    const int L   = threadIdx.x;
    const int bid = blockIdx.x;                 // 0..127 (= b*64 + h)
    const int b   = bid >> 6, h = bid & 63;

    const float LOG_A2 = -8.2854022f;   // -log2(312)
    const float LOG_B2 = -8.4918531f;   // -log2(360)
    const float TAU = 0.95f, KAPPA = 0.025f, XI = 0.025641026f;
    const float RHO = 19.0f, INVRHO = 0.052631579f, TIR = 0.05f;

    __shared__ half1    wS[MAXD * WROWS];     // e^score, [d][j], 29.25 KB
    __shared__ unsigned EA2[204];             // E halfs 0..407 (pos p = j+48)
    __shared__ unsigned EB2[205];             // EB[p] = E[p-1]
    __shared__ unsigned GA2[181];             // G halfs 0..361
    __shared__ unsigned GB2[182];             // GB[c] = G[c-1]
    __shared__ float    s_y[NACC * 64];       // per-phase per-lane partials

    const float* src = scores + ((size_t)(b * MAXD) * 64 + h) * WROWS;
    const size_t dstr = (size_t)64 * WROWS;

    // ---- stage w = e^s into LDS (coalesced global reads) ----
    for (int d = 0; d < MAXD; ++d) {
        #pragma unroll
        for (int q = 0; q < 5; ++q) {
            int j = 64 * q + L;
            if (j < WROWS) wS[d * WROWS + j] = (half1)__expf(src[d * dstr + j]);
        }
    }
    // zero E/G buffers (guards included)
    #pragma unroll
    for (int k = 0; k < 4; ++k) {
        int i = 64 * k + L;
        if (i < 204) EA2[i] = 0u;
        if (i < 205) EB2[i] = 0u;
    }
    #pragma unroll
    for (int k = 0; k < 3; ++k) {
        int i = 64 * k + L;
        if (i < 181) GA2[i] = 0u;
        if (i < 182) GB2[i] = 0u;
    }
    __syncthreads();   // single-wave barrier: cheap; orders wS/zeros

    // ---- register weight caches (fp16 pairs, fixed all iterations) ----
    const unsigned short* wSu = (const unsigned short*)wS;
    const bool colLane = (L < 60);
    const bool rowLane = (L < 52);
    half2v wcolH[6][24];   // col c=6L+m: pair t = (w_{d=2t}, w_{d=2t+1}), w_d = e^s[d][c-48+d]
    half2v wrowH[6][24];   // row j=6L+r: pair t = (w_{47-2t}, w_{46-2t}),  w_d = e^s[d][j]
    #pragma unroll
    for (int m = 0; m < 6; ++m) {
        #pragma unroll
        for (int t = 0; t < 24; ++t) {
            int c = 6 * L + m;
            int j0 = c - MAXD + 2 * t, j1 = j0 + 1;
            unsigned short a  = (colLane && (unsigned)j0 < (unsigned)WROWS) ? wSu[(2*t)*WROWS + j0]   : (unsigned short)0;
            unsigned short bb = (colLane && (unsigned)j1 < (unsigned)WROWS) ? wSu[(2*t+1)*WROWS + j1] : (unsigned short)0;
            wcolH[m][t] = pack2(a, bb);
        }
    }
    #pragma unroll
    for (int r = 0; r < 6; ++r) {
        int j = 6 * L + r;
        #pragma unroll
        for (int t = 0; t < 24; ++t) {
            unsigned short a  = rowLane ? wSu[(47 - 2*t)*WROWS + j] : (unsigned short)0;
            unsigned short bb = rowLane ? wSu[(46 - 2*t)*WROWS + j] : (unsigned short)0;
            wrowH[r][t] = pack2(a, bb);
        }
    }

    // ---- init: Ehat0 = 1/sum(w_row); y0 = sum 2^(ls/RHO + LOG_A2) ----
    const unsigned ONE2 = 0x3C003C00u;
    {
        float y0 = 0.f, eh[6];
        #pragma unroll
        for (int r = 0; r < 6; ++r) {
            float s = 0.f;
            #pragma unroll
            for (int t = 0; t < 24; ++t)
                s = __builtin_amdgcn_fdot2(wrowH[r][t], h2(ONE2), s, false);
            float l = __builtin_amdgcn_logf(s);     // -inf for idle lanes -> y term 0
            eh[r] = __builtin_amdgcn_exp2f(-l);
            y0 += __builtin_amdgcn_exp2f(fmaf(INVRHO, l, LOG_A2));
        }
        if (rowLane) {
            EA2[3*L + 24 + 0] = packf(eh[0], eh[1]);
            EA2[3*L + 24 + 1] = packf(eh[2], eh[3]);
            EA2[3*L + 24 + 2] = packf(eh[4], eh[5]);
            unsigned short* EBu = (unsigned short*)EB2;
            #pragma unroll
            for (int r = 0; r < 6; ++r) EBu[6*L + 49 + r] = f16b(eh[r]);
        }
        s_y[L] = y0;
    }
    __syncthreads();

    const int ebase = 3 * (colLane ? L : 59);
    const int gbase = 3 * (rowLane ? L : 51);
    float denv[6], ehv[6];

    // ---- Sinkhorn iterations: one wave, lane-local band dots ----
    for (int it = 0; it < NITER; ++it) {
        // col phase: Ghat_c = (sum_d w * Ehat)^-TAU
        unsigned eA[27], eB[27];
        #pragma unroll
        for (int t = 0; t < 27; ++t) { eA[t] = EA2[ebase + t]; eB[t] = EB2[ebase + t]; }
        float yc = 0.f, gh[6];
        #pragma unroll
        for (int m = 0; m < 6; ++m) {
            float acc = 0.f;
            const int off = (m + 1) >> 1;
            if (m & 1) {
                #pragma unroll
                for (int t = 0; t < 24; ++t)
                    acc = __builtin_amdgcn_fdot2(wcolH[m][t], h2(eB[off + t]), acc, false);
            } else {
                #pragma unroll
                for (int t = 0; t < 24; ++t)
                    acc = __builtin_amdgcn_fdot2(wcolH[m][t], h2(eA[off + t]), acc, false);
            }
            float lc = __builtin_amdgcn_logf(acc);
            gh[m] = __builtin_amdgcn_exp2f(-TAU * lc);
            yc += __builtin_amdgcn_exp2f(fmaf(TIR, lc, LOG_B2));
        }
        if (colLane) {
            GA2[3*L + 0] = packf(gh[0], gh[1]);
            GA2[3*L + 1] = packf(gh[2], gh[3]);
            GA2[3*L + 2] = packf(gh[4], gh[5]);
            unsigned short* GBu = (unsigned short*)GB2;
            #pragma unroll
            for (int m = 0; m < 6; ++m) GBu[6*L + 1 + m] = f16b(gh[m]);
        }
        s_y[(1 + 2*it) * 64 + L] = yc;
        __syncthreads();

        // row phase: Ehat_j = (sum_d w * Ghat)^-TAU
        unsigned gA[27], gB[27];
        #pragma unroll
        for (int t = 0; t < 27; ++t) { gA[t] = GA2[gbase + t]; gB[t] = GB2[gbase + t]; }
        float yr = 0.f;
        #pragma unroll
        for (int r = 0; r < 6; ++r) {
            float acc = 0.f;
            const int off = (r >> 1) + 1;
            if (r & 1) {
                #pragma unroll
                for (int t = 0; t < 24; ++t)
                    acc = __builtin_amdgcn_fdot2(wrowH[r][t], h2(gA[off + t]), acc, false);
            } else {
                #pragma unroll
                for (int t = 0; t < 24; ++t)
                    acc = __builtin_amdgcn_fdot2(wrowH[r][t], h2(gB[off + t]), acc, false);
            }
            denv[r] = acc;
            float lr = __builtin_amdgcn_logf(acc);
            ehv[r] = __builtin_amdgcn_exp2f(-TAU * lr);
            yr += __builtin_amdgcn_exp2f(fmaf(TIR, lr, LOG_A2));
        }
        if (rowLane) {
            EA2[3*L + 24 + 0] = packf(ehv[0], ehv[1]);
            EA2[3*L + 24 + 1] = packf(ehv[2], ehv[3]);
            EA2[3*L + 24 + 2] = packf(ehv[4], ehv[5]);
            unsigned short* EBu = (unsigned short*)EB2;
            #pragma unroll
            for (int r = 0; r < 6; ++r) EBu[6*L + 49 + r] = f16b(ehv[r]);
        }
        s_y[(2 + 2*it) * 64 + L] = yr;
        __syncthreads();
    }

    // ---- reduce the 21 phase partials (DPP) -> R[], uniform ----
    float R[NACC];
    #pragma unroll
    for (int p = 0; p < NACC; ++p) {
        float s = dpp_sum64(s_y[p * 64 + L]);
        s = __shfl(s, 63);
        R[p] = __builtin_amdgcn_logf(s);
    }

    // ---- scalar recurrence for the uniform shifts ----
    float fsh   = -LOG_B2;
    float sminF = fsh - RHO * R[0];
    float gsh   = 0.f;
    #pragma unroll
    for (int it = 0; it < NITER; ++it) {
        float Cg = TAU * (LOG_B2 - fsh) - KAPPA * sminF;
        float sg = Cg - RHO * R[1 + 2*it];
        gsh = Cg + XI * sg;
        float sminG = (1.f + XI) * sg;
        float Cf = TAU * (LOG_A2 - gsh) - KAPPA * sminG;
        float sf = Cf - RHO * R[2 + 2*it];
        fsh = Cf + XI * sf;
        sminF = (1.f + XI) * sf;
    }

    // ---- epilogue: disparity from final windows ----
    if (rowLane) {
        unsigned gAe[27], gBe[27];
        #pragma unroll
        for (int t = 0; t < 27; ++t) { gAe[t] = GA2[gbase + t]; gBe[t] = GB2[gbase + t]; }
        float escale = __builtin_amdgcn_exp2f(fsh + gsh);
        #pragma unroll
        for (int r = 0; r < 6; ++r) {
            float num = 0.f;
            const int off = (r >> 1) + 1;
            #pragma unroll
            for (int t = 0; t < 24; ++t) {
                half2v dc; dc[0] = (half1)(float)(47 - 2*t); dc[1] = (half1)(float)(46 - 2*t);
                half2v wd = wrowH[r][t] * dc;                // v_pk_mul_f16
                unsigned gp = (r & 1) ? gAe[off + t] : gBe[off + t];
                num = __builtin_amdgcn_fdot2(wd, h2(gp), num, false);
            }
            float E = escale * ehv[r];
            float mass = fmaxf(E * denv[r], 1e-8f);
            out[(size_t)bid * WROWS + 6*L + r] = (E * num) / mass;
        }
    }
}

extern "C" void kernel_launch(void* const* d_in, const int* in_sizes, int n_in,
                              void* d_out, int out_size, void* d_ws, size_t ws_size,
                              hipStream_t stream) {
    const float* scores = (const float*)d_in[0];
    float* out = (float*)d_out;
    ot_disp_kernel<<<128, 64, 0, stream>>>(scores, out);
}

// Round 11
// 27.606 us; speedup vs baseline: 2.6436x; 2.6436x over previous
//
#include <hip/hip_runtime.h>
#include <math.h>

// Banded unbalanced Sinkhorn OT -> disparity. One (b,h) problem per block,
// 4 waves (256 threads), lane owns cols {2t,2t+1} and rows {2t,2t+1}.
// Hat-recurrence: Ghat = (sum w*Ehat)^-tau, Ehat' = (sum w*Ghat)^-tau; all
// uniform shifts deferred to an end-of-kernel scalar recurrence over 21
// reduction values. E/G in LDS as packed fp16 dwords; every window is 25
// consecutive aligned dwords (ds_read2-mergeable, no replicas). Weights are
// 96 register-resident half2; band sums via v_dot2_f32_f16.

typedef _Float16 half1;
typedef _Float16 half2v __attribute__((ext_vector_type(2)));

#define MAXD   48
#define WROWS  312
#define CCOLS  360
#define NITER  10
#define NT     256
#define NACC   21

__device__ __forceinline__ half2v h2(unsigned v) { return __builtin_bit_cast(half2v, v); }
__device__ __forceinline__ unsigned packf(float x, float y) {
    half2v v; v[0] = (half1)x; v[1] = (half1)y;
    return __builtin_bit_cast(unsigned, v);
}
__device__ __forceinline__ float fdot2(unsigned a, unsigned b, float c) {
    return __builtin_amdgcn_fdot2(h2(a), h2(b), c, false);
}
template <int CTRL>
__device__ __forceinline__ float dpp_add(float x, float acc) {
    int y = __builtin_amdgcn_update_dpp(0, __float_as_int(x), CTRL, 0xf, 0xf, true);
    return acc + __int_as_float(y);
}
__device__ __forceinline__ float dpp_sum64(float x) {   // valid in lane 63
    x = dpp_add<0x111>(x, x);
    x = dpp_add<0x112>(x, x);
    x = dpp_add<0x114>(x, x);
    x = dpp_add<0x118>(x, x);
    x = dpp_add<0x142>(x, x);
    x = dpp_add<0x143>(x, x);
    return x;
}

__global__ __launch_bounds__(NT, 1)
void ot_disp_kernel(const float* __restrict__ scores, float* __restrict__ out) {
    const int tid = threadIdx.x;
    const int wid = tid >> 6;
    const int bid = blockIdx.x;                 // 0..127 (= b*64 + h)
    const int b   = bid >> 6, h = bid & 63;

    const float LOG_A2 = -8.2854022f;   // -log2(312)
    const float LOG_B2 = -8.4918531f;   // -log2(360)
    const float TAU = 0.95f, KAPPA = 0.025f, XI = 0.025641026f;
    const float RHO = 19.0f, INVRHO = 0.052631579f, TIR = 0.05f;

    __shared__ unsigned E2[204];        // halfs: E at bufpos p=j+48, p in [0,408)
    __shared__ unsigned G2[180];        // halfs: G[c], c in [0,360)
    __shared__ float    s_red[NACC * 4];

    const float* src = scores + ((size_t)(b * MAXD) * 64 + h) * WROWS;
    const size_t dstr = (size_t)64 * WROWS;

    const bool colAct = (tid < 180);
    const bool rowAct = (tid < 156);
    const int  j0 = 2 * tid;            // rows j0, j0+1; cols c0=2*tid, c0+1

    // ---- register weight caches (96 half2), gathered straight from global ----
    unsigned wcolE[24], wcolO[23], wcolOe;   // c0 pairs (d=2t,2t+1); c1 (2t+1,2t+2); c1 edge (0,47)
    unsigned wrowE[24], wrowO[23], wrowOe;   // j1 pairs (47-2t,46-2t); j0 (46-2t,45-2t); j0 edge (47,0)
    {
        float e0_even = 0.f, e1_carry = 0.f, e1_0 = 0.f;
        #pragma unroll
        for (int k = 0; k < 48; ++k) {
            int ja = 2 * tid - 48 + k;                 // c0's j at d=k
            bool va = colAct && ((unsigned)ja < (unsigned)WROWS);
            float xa = va ? __expf(src[(size_t)k * dstr + (va ? ja : 0)]) : 0.f;
            int jb = ja + 1;                           // c1's j at d=k
            bool vb = colAct && ((unsigned)jb < (unsigned)WROWS);
            float xb = vb ? __expf(src[(size_t)k * dstr + (vb ? jb : 0)]) : 0.f;
            if (k & 1) wcolE[k >> 1] = packf(e0_even, xa);
            else       e0_even = xa;
            if (k == 0)      e1_0 = xb;
            else if (k & 1)  e1_carry = xb;
            else             wcolO[(k >> 1) - 1] = packf(e1_carry, xb);
            if (k == 47)     wcolOe = packf(e1_0, xb);
        }
    }
    {
        const float rm = rowAct ? 1.f : 0.f;
        const int   jj = rowAct ? j0 : 0;
        float a0 = 0.f, b_prev = 0.f;
        #pragma unroll
        for (int t = 0; t < 24; ++t) {
            int dA = 47 - 2 * t, dB = 46 - 2 * t;
            float2 A = *(const float2*)(src + (size_t)dA * dstr + jj);
            float2 B = *(const float2*)(src + (size_t)dB * dstr + jj);
            float eAx = rm * __expf(A.x), eAy = rm * __expf(A.y);
            float eBx = rm * __expf(B.x), eBy = rm * __expf(B.y);
            wrowE[t] = packf(eAy, eBy);
            if (t == 0) a0 = eAx;
            else        wrowO[t - 1] = packf(b_prev, eAx);
            b_prev = eBx;
        }
        wrowOe = packf(a0, b_prev);   // (w47, w0) for j0
    }

    const unsigned ONE2 = 0x3C003C00u;

    // ---- init: Ehat0 = 1/sum(w_row); y0 partial -> s_red[0] ----
    {
        float s1 = 0.f, s0 = 0.f;
        #pragma unroll
        for (int t = 0; t < 24; ++t) s1 = fdot2(wrowE[t], ONE2, s1);
        #pragma unroll
        for (int t = 0; t < 23; ++t) s0 = fdot2(wrowO[t], ONE2, s0);
        s0 = fdot2(wrowOe, ONE2, s0);
        float l0 = __builtin_amdgcn_logf(s0), l1 = __builtin_amdgcn_logf(s1);
        float y = __builtin_amdgcn_exp2f(fmaf(INVRHO, l0, LOG_A2))
                + __builtin_amdgcn_exp2f(fmaf(INVRHO, l1, LOG_A2));
        if (rowAct)
            E2[tid + 24] = packf(__builtin_amdgcn_exp2f(-l0), __builtin_amdgcn_exp2f(-l1));
        float ts = dpp_sum64(y);
        if ((tid & 63) == 63) s_red[0 * 4 + wid] = ts;
    }
    if (tid < 48) E2[tid < 24 ? tid : 156 + tid] = 0u;   // guards p<48, p>=360
    __syncthreads();

    // ---- Sinkhorn loop: 2 barriers/iter, lane-local dot2 bands ----
    float den0 = 0.f, den1 = 0.f, eh0 = 0.f, eh1 = 0.f;
    unsigned v[25];
    const int ub = colAct ? tid : 179;
    const int vb = rowAct ? tid : 155;
    for (int it = 0; it < NITER; ++it) {
        // col phase: Ghat = (sum w*Ehat)^-tau for c0, c1
        unsigned u[25];
        #pragma unroll
        for (int t = 0; t < 25; ++t) u[t] = E2[ub + t];
        float p0 = 0.f, p1 = 0.f, q0 = 0.f, q1 = 0.f;
        #pragma unroll
        for (int t = 0; t < 24; ++t) { float& d = (t & 1) ? p1 : p0; d = fdot2(wcolE[t], u[t], d); }
        #pragma unroll
        for (int t = 0; t < 23; ++t) { float& d = (t & 1) ? q1 : q0; d = fdot2(wcolO[t], u[t + 1], d); }
        {
            unsigned eop = (u[0] >> 16) | (u[24] << 16);   // (hi(u0), lo(u24))
            q0 = fdot2(wcolOe, eop, q0);
        }
        float sA = p0 + p1, sB = q0 + q1;
        float lA = __builtin_amdgcn_logf(sA), lB = __builtin_amdgcn_logf(sB);
        float yc = __builtin_amdgcn_exp2f(fmaf(TIR, lA, LOG_B2))
                 + __builtin_amdgcn_exp2f(fmaf(TIR, lB, LOG_B2));
        if (colAct)
            G2[tid] = packf(__builtin_amdgcn_exp2f(-TAU * lA), __builtin_amdgcn_exp2f(-TAU * lB));
        float ts = dpp_sum64(yc);
        if ((tid & 63) == 63) s_red[(1 + 2 * it) * 4 + wid] = ts;
        __syncthreads();

        // row phase: Ehat = (sum w*Ghat)^-tau for j0, j1
        #pragma unroll
        for (int t = 0; t < 25; ++t) v[t] = G2[vb + t];
        float r0 = 0.f, r1 = 0.f, s0a = 0.f, s1a = 0.f;
        #pragma unroll
        for (int t = 0; t < 24; ++t) { float& d = (t & 1) ? r1 : r0; d = fdot2(wrowE[t], v[t + 1], d); }
        #pragma unroll
        for (int t = 0; t < 23; ++t) { float& d = (t & 1) ? s1a : s0a; d = fdot2(wrowO[t], v[t + 1], d); }
        {
            unsigned eop = (v[0] >> 16) | (v[24] << 16);   // (hi(v0), lo(v24))
            s0a = fdot2(wrowOe, eop, s0a);
        }
        den0 = s0a + s1a; den1 = r0 + r1;
        float l0 = __builtin_amdgcn_logf(den0), l1 = __builtin_amdgcn_logf(den1);
        eh0 = __builtin_amdgcn_exp2f(-TAU * l0);
        eh1 = __builtin_amdgcn_exp2f(-TAU * l1);
        float yr = __builtin_amdgcn_exp2f(fmaf(TIR, l0, LOG_A2))
                 + __builtin_amdgcn_exp2f(fmaf(TIR, l1, LOG_A2));
        if (rowAct) E2[tid + 24] = packf(eh0, eh1);
        float ts2 = dpp_sum64(yr);
        if ((tid & 63) == 63) s_red[(2 + 2 * it) * 4 + wid] = ts2;
        __syncthreads();
    }

    // ---- scalar recurrence from the 21 reduction values (uniform) ----
    float fsh = -LOG_B2, gsh = 0.f;
    {
        float Rv[NACC];
        #pragma unroll
        for (int p = 0; p < NACC; ++p) {
            float s = (s_red[4 * p] + s_red[4 * p + 1]) + (s_red[4 * p + 2] + s_red[4 * p + 3]);
            Rv[p] = __builtin_amdgcn_logf(s);
        }
        float sminF = fsh - RHO * Rv[0];
        #pragma unroll
        for (int it = 0; it < NITER; ++it) {
            float Cg = TAU * (LOG_B2 - fsh) - KAPPA * sminF;
            float sg = Cg - RHO * Rv[1 + 2 * it];
            gsh = Cg + XI * sg;
            float sminG = (1.f + XI) * sg;
            float Cf = TAU * (LOG_A2 - gsh) - KAPPA * sminG;
            float sf = Cf - RHO * Rv[2 + 2 * it];
            fsh = Cf + XI * sf;
            sminF = (1.f + XI) * sf;
        }
    }

    // ---- epilogue: disparity from final G window (still in v/regs) ----
    if (rowAct) {
        float n1 = 0.f, n0 = 0.f;
        #pragma unroll
        for (int t = 0; t < 24; ++t) {
            half2v dc; dc[0] = (half1)(float)(47 - 2 * t); dc[1] = (half1)(float)(46 - 2 * t);
            half2v wd = h2(wrowE[t]) * dc;
            n1 = __builtin_amdgcn_fdot2(wd, h2(v[t + 1]), n1, false);
        }
        #pragma unroll
        for (int t = 0; t < 23; ++t) {
            half2v dc; dc[0] = (half1)(float)(46 - 2 * t); dc[1] = (half1)(float)(45 - 2 * t);
            half2v wd = h2(wrowO[t]) * dc;
            n0 = __builtin_amdgcn_fdot2(wd, h2(v[t + 1]), n0, false);
        }
        {
            unsigned eop = (v[0] >> 16) | (v[24] << 16);
            half2v dc; dc[0] = (half1)47.f; dc[1] = (half1)0.f;
            half2v wd = h2(wrowOe) * dc;
            n0 = __builtin_amdgcn_fdot2(wd, h2(eop), n0, false);
        }
        float esc = __builtin_amdgcn_exp2f(fsh + gsh);
        float E0 = esc * eh0, E1 = esc * eh1;
        float2 o;
        o.x = (E0 * n0) / fmaxf(E0 * den0, 1e-8f);
        o.y = (E1 * n1) / fmaxf(E1 * den1, 1e-8f);
        *(float2*)(out + (size_t)bid * WROWS + j0) = o;
    }
}

extern "C" void kernel_launch(void* const* d_in, const int* in_sizes, int n_in,
                              void* d_out, int out_size, void* d_ws, size_t ws_size,
                              hipStream_t stream) {
    const float* scores = (const float*)d_in[0];
    float* out = (float*)d_out;
    ot_disp_kernel<<<128, NT, 0, stream>>>(scores, out);
}

// Round 12
// 24.029 us; speedup vs baseline: 3.0372x; 1.1489x over previous
//
#include <hip/hip_runtime.h>
#include <math.h>

// Banded unbalanced Sinkhorn OT -> disparity. One (b,h) problem per block,
// 6 waves (384 threads): lane owns ONE col c=tid and ONE row j=tid.
// Hat-recurrence: Ghat = (sum w*Ehat)^-tau, Ehat' = (sum w*Ghat)^-tau; the
// uniform shifts ride in an end-of-kernel scalar recurrence over 21 stored
// reduction values (per-lane partials kept in registers, reduced once).
// E/G in LDS fp16 with one shifted replica (EA/EB, GA/GB) so every lane's
// 48-half window is 24 consecutive dwords. Weights: 48 register dwords/lane
// gathered straight from global (no staging pass). Band MACs: v_dot2_f32_f16.

typedef _Float16 half1;
typedef _Float16 half2v __attribute__((ext_vector_type(2)));

#define MAXD   48
#define WROWS  312
#define CCOLS  360
#define NITER  10
#define NT     384
#define NWAVE  6
#define NACC   21

__device__ __forceinline__ half2v h2(unsigned v) { return __builtin_bit_cast(half2v, v); }
__device__ __forceinline__ unsigned packf(float x, float y) {
    half2v v; v[0] = (half1)x; v[1] = (half1)y;
    return __builtin_bit_cast(unsigned, v);
}
__device__ __forceinline__ float fdot2(unsigned a, unsigned b, float c) {
    return __builtin_amdgcn_fdot2(h2(a), h2(b), c, false);
}
__device__ __forceinline__ float fdot2h(half2v a, unsigned b, float c) {
    return __builtin_amdgcn_fdot2(a, h2(b), c, false);
}
template <int CTRL>
__device__ __forceinline__ float dpp_add(float x, float acc) {
    int y = __builtin_amdgcn_update_dpp(0, __float_as_int(x), CTRL, 0xf, 0xf, true);
    return acc + __int_as_float(y);
}
__device__ __forceinline__ float dpp_sum64(float x) {   // valid in lane 63
    x = dpp_add<0x111>(x, x);
    x = dpp_add<0x112>(x, x);
    x = dpp_add<0x114>(x, x);
    x = dpp_add<0x118>(x, x);
    x = dpp_add<0x142>(x, x);
    x = dpp_add<0x143>(x, x);
    return x;
}

__global__ __launch_bounds__(NT, 2)
void ot_disp_kernel(const float* __restrict__ scores, float* __restrict__ out) {
    const int tid = threadIdx.x;
    const int wid = tid >> 6;
    const int bid = blockIdx.x;                 // 0..127 (= b*64 + h)
    const int b   = bid >> 6, h = bid & 63;

    const float LOG_A2 = -8.2854022f;   // -log2(312)
    const float LOG_B2 = -8.4918531f;   // -log2(360)
    const float TAU = 0.95f, KAPPA = 0.025f, XI = 0.025641026f;
    const float RHO = 19.0f, INVRHO = 0.052631579f, TIR = 0.05f;

    // E at bufpos p=j+48 (halfs 0..407); EB[p+1] = E[p]. G at c (halfs 0..359);
    // GB[c+1] = G[c].
    __shared__ unsigned EA2[204], EB2[204], GA2[180], GB2[181];
    __shared__ float s_red[NACC * NWAVE];
    half1* const EAh = (half1*)EA2;  half1* const EBh = (half1*)EB2;
    half1* const GAh = (half1*)GA2;  half1* const GBh = (half1*)GB2;

    // guard zeros (ranges never alias written halfs: E written p=48..359
    // -> EA halfs 48..359, EB halfs 49..360)
    if (tid < 24) { EA2[tid] = 0u; EA2[180 + tid] = 0u; EB2[tid] = 0u; }
    if (tid < 23) EB2[181 + tid] = 0u;
    if (tid == 30) { EBh[48] = (half1)0.f; EBh[361] = (half1)0.f; }

    const bool rowAct = (tid < WROWS);
    const bool colW   = (tid >= 1 && tid < CCOLS);
    const int  c = (tid < CCOLS) ? tid : (CCOLS - 1);
    const int  j = rowAct ? tid : (WROWS - 1);

    const float* src = scores + ((size_t)(b * MAXD) * 64 + h) * WROWS;
    const size_t dstr = (size_t)64 * WROWS;

    // ---- register weight caches (48 dwords), straight from global ----
    unsigned wcol[24];   // pair t = (w_{d=2t}, w_{d=2t+1}),  w_d = e^s[d][c-48+d] (0 if OOB)
    unsigned wrow[24];   // pair t = (w_{d=47-2t}, w_{d=46-2t}), w_d = e^s[d][j]
    #pragma unroll
    for (int t = 0; t < 24; ++t) {
        int j0 = c - MAXD + 2 * t;
        int j1 = j0 + 1;
        bool v0 = (unsigned)j0 < (unsigned)WROWS;
        bool v1 = (unsigned)j1 < (unsigned)WROWS;
        float x0 = v0 ? __expf(src[(size_t)(2 * t) * dstr + (v0 ? j0 : 0)]) : 0.f;
        float x1 = v1 ? __expf(src[(size_t)(2 * t + 1) * dstr + (v1 ? j1 : 0)]) : 0.f;
        wcol[t] = packf(x0, x1);
    }
    #pragma unroll
    for (int t = 0; t < 24; ++t) {
        float x0 = __expf(src[(size_t)(47 - 2 * t) * dstr + j]);
        float x1 = __expf(src[(size_t)(46 - 2 * t) * dstr + j]);
        wrow[t] = packf(x0, x1);
    }

    // window base pointers (24 consecutive dwords each, parity-resolved)
    const unsigned* const ecp = (c & 1) ? (EB2 + ((c + 1) >> 1)) : (EA2 + (c >> 1));
    const unsigned* const grp = (j & 1) ? (GA2 + ((j + 1) >> 1)) : (GB2 + ((j + 2) >> 1));

    // ---- init: Ehat0 = 1/sum(w_row); y[0] partial in reg ----
    const unsigned ONE2 = 0x3C003C00u;
    float y[NACC];
    {
        float s0 = 0.f, s1 = 0.f;
        #pragma unroll
        for (int t = 0; t < 24; t += 2) {
            s0 = fdot2(wrow[t], ONE2, s0);
            s1 = fdot2(wrow[t + 1], ONE2, s1);
        }
        float l  = __builtin_amdgcn_logf(s0 + s1);
        float e0 = __builtin_amdgcn_exp2f(-l);
        if (rowAct) { EAh[j + 48] = (half1)e0; EBh[j + 49] = (half1)e0; }
        y[0] = rowAct ? __builtin_amdgcn_exp2f(fmaf(INVRHO, l, LOG_A2)) : 0.f;
    }
    __syncthreads();   // B0: guards + init E visible

    // ---- Sinkhorn loop: 2 barriers/iter, lane-local dot2 bands ----
    float den = 0.f, ehv = 0.f;
    #pragma unroll
    for (int it = 0; it < NITER; ++it) {
        // col phase: Ghat_c = (sum_d w * Ehat)^-tau
        float a0 = 0.f, a1 = 0.f;
        #pragma unroll
        for (int t = 0; t < 24; t += 2) {
            a0 = fdot2(wcol[t],     ecp[t],     a0);
            a1 = fdot2(wcol[t + 1], ecp[t + 1], a1);
        }
        float lc = __builtin_amdgcn_logf(a0 + a1);
        float gh = __builtin_amdgcn_exp2f(-TAU * lc);
        if (colW) { GAh[c] = (half1)gh; GBh[c + 1] = (half1)gh; }
        y[1 + 2 * it] = colW ? __builtin_amdgcn_exp2f(fmaf(TIR, lc, LOG_B2)) : 0.f;
        __syncthreads();

        // row phase: Ehat_j = (sum_d w * Ghat)^-tau
        float b0 = 0.f, b1 = 0.f;
        #pragma unroll
        for (int t = 0; t < 24; t += 2) {
            b0 = fdot2(wrow[t],     grp[t],     b0);
            b1 = fdot2(wrow[t + 1], grp[t + 1], b1);
        }
        den = b0 + b1;
        float lr = __builtin_amdgcn_logf(den);
        ehv = __builtin_amdgcn_exp2f(-TAU * lr);
        if (rowAct) { EAh[j + 48] = (half1)ehv; EBh[j + 49] = (half1)ehv; }
        y[2 + 2 * it] = rowAct ? __builtin_amdgcn_exp2f(fmaf(TIR, lr, LOG_A2)) : 0.f;
        __syncthreads();
    }

    // ---- reduce the 21 per-lane partials once (DPP + 6 slots each) ----
    #pragma unroll
    for (int p = 0; p < NACC; ++p) {
        float s = dpp_sum64(y[p]);
        if ((tid & 63) == 63) s_red[p * NWAVE + wid] = s;
    }
    __syncthreads();

    // ---- uniform scalar recurrence from the 21 reduction values ----
    float fsh = -LOG_B2, gsh = 0.f;
    {
        float R[NACC];
        #pragma unroll
        for (int p = 0; p < NACC; ++p) {
            const float* rp = s_red + p * NWAVE;
            float s = ((rp[0] + rp[1]) + (rp[2] + rp[3])) + (rp[4] + rp[5]);
            R[p] = __builtin_amdgcn_logf(s);
        }
        float sminF = fsh - RHO * R[0];
        #pragma unroll
        for (int it = 0; it < NITER; ++it) {
            float Cg = TAU * (LOG_B2 - fsh) - KAPPA * sminF;
            float sg = Cg - RHO * R[1 + 2 * it];
            gsh = Cg + XI * sg;
            float sminG = (1.f + XI) * sg;
            float Cf = TAU * (LOG_A2 - gsh) - KAPPA * sminG;
            float sf = Cf - RHO * R[2 + 2 * it];
            fsh = Cf + XI * sf;
            sminF = (1.f + XI) * sf;
        }
    }

    // ---- epilogue: disparity (G window re-read; den/ehv from last phase) ----
    if (rowAct) {
        float n0 = 0.f, n1 = 0.f;
        #pragma unroll
        for (int t = 0; t < 24; ++t) {
            half2v dc; dc[0] = (half1)(float)(47 - 2 * t); dc[1] = (half1)(float)(46 - 2 * t);
            half2v wd = h2(wrow[t]) * dc;             // v_pk_mul_f16
            float& nn = (t & 1) ? n1 : n0;
            nn = fdot2h(wd, grp[t], nn);
        }
        float E = __builtin_amdgcn_exp2f(fsh + gsh) * ehv;
        float mass = fmaxf(E * den, 1e-8f);
        out[(size_t)bid * WROWS + j] = (E * (n0 + n1)) / mass;
    }
}

extern "C" void kernel_launch(void* const* d_in, const int* in_sizes, int n_in,
                              void* d_out, int out_size, void* d_ws, size_t ws_size,
                              hipStream_t stream) {
    const float* scores = (const float*)d_in[0];
    float* out = (float*)d_out;
    ot_disp_kernel<<<128, NT, 0, stream>>>(scores, out);
}